// Round 7
// baseline (272.703 us; speedup 1.0000x reference)
//
#include <hip/hip_runtime.h>

#define T_TOK 2048
#define HID   1024
#define FFN   2048
#define NEXP  8
#define MAX_SLOTS 32

typedef __attribute__((ext_vector_type(8))) short bf16x8;
typedef __attribute__((ext_vector_type(4))) float f32x4;

__device__ __forceinline__ short f2bf(float f) {
    unsigned u = __builtin_bit_cast(unsigned, f);
    u = (u + 0x7fffu + ((u >> 16) & 1u)) >> 16;
    return (short)u;
}

__device__ __forceinline__ float gelu_exact(float x) {
    return 0.5f * x * (1.0f + erff(x * 0.70710678118654752f));
}

// async 16B global -> LDS DMA; HW places lane i at base + i*16.
__device__ __forceinline__ void async_cp16(const short* g, short* l) {
    __builtin_amdgcn_global_load_lds(
        (const __attribute__((address_space(1))) unsigned int*)g,
        (__attribute__((address_space(3))) unsigned int*)l, 16, 0, 0);
}

// ---- weight transpose: W[e][K][N] f32 -> pre-swizzled bf16 panels ---------
// Panel (npanel,kpanel) = 128n x 64k = 8192 shorts (16 KB), layout:
//   element (n, k=kc*8+j) at n*64 + ((kc + n)&7)*8 + j   (chunk-rotated)
// Panels ordered [e][npanel][kpanel].
__device__ __forceinline__ void wtrans_body(
        const float* __restrict__ W, short* __restrict__ WT,
        int K, int N, int e, int kpanel, int npair) {
    int tid = threadIdx.x;
    int w = tid >> 6, l = tid & 63;
    int n4 = npair * 256 + l * 4;
    int npanel = n4 >> 7, n_in = n4 & 127;
    short* dstp = WT + (size_t)e * K * N
                + ((size_t)npanel * (K >> 6) + kpanel) * 8192;
    const float* We = W + (size_t)e * K * N;
#pragma unroll
    for (int h = 0; h < 2; h++) {
        int kc = w + h * 4;
        const float* src = We + (size_t)(kpanel * 64 + kc * 8) * N + n4;
        float4 v[8];
#pragma unroll
        for (int r = 0; r < 8; r++) v[r] = *(const float4*)(src + (size_t)r * N);
#pragma unroll
        for (int j = 0; j < 4; j++) {
            bf16x8 o = {f2bf(((const float*)&v[0])[j]), f2bf(((const float*)&v[1])[j]),
                        f2bf(((const float*)&v[2])[j]), f2bf(((const float*)&v[3])[j]),
                        f2bf(((const float*)&v[4])[j]), f2bf(((const float*)&v[5])[j]),
                        f2bf(((const float*)&v[6])[j]), f2bf(((const float*)&v[7])[j])};
            int n = n_in + j;
            *(bf16x8*)(dstp + n * 64 + ((kc + n) & 7) * 8) = o;
        }
    }
}

// ---- fused prep: wtrans W1 | wtrans W2 | xcvt | initout | bucket ----------
__global__ __launch_bounds__(256) void prep_kernel(
        const float* __restrict__ x, const int* __restrict__ idx,
        const float* __restrict__ b2,
        const float* __restrict__ W1, const float* __restrict__ W2,
        short* __restrict__ xb, float* __restrict__ out,
        short* __restrict__ W1T, short* __restrict__ W2T,
        int* __restrict__ offs, int* __restrict__ cnts,
        int* __restrict__ tokl,
        int* __restrict__ slot_e, int* __restrict__ slot_t0) {
    int bx = blockIdx.x;
    int tid = threadIdx.x;
    if (bx < 1024) {                       // W1: 8e x 16 kpanel x 8 npair
        int e = bx >> 7, rem = bx & 127;
        wtrans_body(W1, W1T, HID, FFN, e, rem >> 3, rem & 7);
    } else if (bx < 2048) {                // W2: 8e x 32 kpanel x 4 npair
        int b = bx - 1024;
        int e = b >> 7, rem = b & 127;
        wtrans_body(W2, W2T, FFN, HID, e, rem >> 2, rem & 3);
    } else if (bx < 3072) {                // x f32 -> bf16
        int i = ((bx - 2048) * 256 + tid) * 8;
        float4 v0 = *(const float4*)(x + i);
        float4 v1 = *(const float4*)(x + i + 4);
        bf16x8 r = {f2bf(v0.x), f2bf(v0.y), f2bf(v0.z), f2bf(v0.w),
                    f2bf(v1.x), f2bf(v1.y), f2bf(v1.z), f2bf(v1.w)};
        *(bf16x8*)(xb + i) = r;
    } else if (bx < 5120) {                // out[t] = b2[idx[t]]
        int t = bx - 3072;
        int e = idx[t];
        ((float4*)(out + (size_t)t * HID))[tid] =
            ((const float4*)(b2 + (size_t)e * HID))[tid];
    } else {                               // bucket + 128-granular slot list
        __shared__ int c[NEXP], cur[NEXP], o[NEXP];
        if (tid < NEXP) { c[tid] = 0; cur[tid] = 0; }
        __syncthreads();
        for (int t = tid; t < T_TOK; t += 256) atomicAdd(&c[idx[t]], 1);
        __syncthreads();
        if (tid == 0) {
            int s = 0;
            for (int e = 0; e < NEXP; e++) { o[e] = s; s += c[e]; }
            int ns = 0;
            for (int e = 0; e < NEXP; e++)
                for (int t0 = 0; t0 < c[e]; t0 += 128) {
                    slot_e[ns] = e; slot_t0[ns] = t0; ns++;
                }
            for (; ns < MAX_SLOTS; ns++) slot_e[ns] = -1;
        }
        __syncthreads();
        if (tid < NEXP) { offs[tid] = o[tid]; cnts[tid] = c[tid]; }
        for (int t = tid; t < T_TOK; t += 256) {
            int e = idx[t];
            int p = o[e] + atomicAdd(&cur[e], 1);
            tokl[p] = t;
        }
    }
}

// ---- GEMM1: hg = gelu(xb_gathered @ W1T + b1) ------------------------------
// 128m x 128n block, 4 waves (64x64 each), BK=64, dbuf single-barrier DMA.
// grid (FFN/128, MAX_SLOTS).
__global__ __launch_bounds__(256) void gemm1_kernel(
        const short* __restrict__ xb, const short* __restrict__ W1T,
        const float* __restrict__ b1,
        const int* __restrict__ offs, const int* __restrict__ cnts,
        const int* __restrict__ tokl,
        const int* __restrict__ slot_e, const int* __restrict__ slot_t0,
        short* __restrict__ hg) {
    int s = blockIdx.y;
    int e = slot_e[s];
    if (e < 0) return;
    int t0 = slot_t0[s], count = cnts[e], off = offs[e];
    int n0 = blockIdx.x * 128;

    __shared__ short As[2][128 * 64];   // 16 KB each
    __shared__ short Bs[2][128 * 64];

    int tid = threadIdx.x;
    int w = tid >> 6, l = tid & 63, l15 = l & 15, quad = l >> 4;
    int wm = (w >> 1) * 64, wn = (w & 1) * 64;

    // A staging sources (rows fixed, column advances with kt)
    const short* srcA[4];
    int arow[4];
#pragma unroll
    for (int i = 0; i < 4; i++) {
        int row = w * 32 + i * 8 + (l >> 3);
        arow[i] = row;
        int c = ((l & 7) - row) & 7;
        int p = t0 + row;
        int g = tokl[off + (p < count ? p : count - 1)];
        srcA[i] = xb + (size_t)g * HID + c * 8;
    }
    int sbase = w * 2048 + l * 8;       // + i*512 per instr (shorts)

    const short* Bpan = W1T + (size_t)e * (FFN * HID)
                      + (size_t)(n0 >> 7) * ((HID >> 6) * 8192);

    f32x4 acc[4][4];
#pragma unroll
    for (int i = 0; i < 4; i++)
#pragma unroll
        for (int j = 0; j < 4; j++) acc[i][j] = (f32x4){0.f, 0.f, 0.f, 0.f};

#define G1_DMA(BUF, KT) {                                                    \
    _Pragma("unroll") for (int i = 0; i < 4; i++)                            \
        async_cp16(srcA[i] + (KT) * 64, &As[BUF][sbase + i * 512]);          \
    const short* bp = Bpan + (size_t)(KT) * 8192;                            \
    _Pragma("unroll") for (int i = 0; i < 4; i++)                            \
        async_cp16(bp + sbase + i * 512, &Bs[BUF][sbase + i * 512]); }

    G1_DMA(0, 0);
    const int NK = HID / 64;
    for (int kt = 0; kt < NK; kt++) {
        __syncthreads();                 // drains this iter's buffer
        int cur = kt & 1;
        if (kt + 1 < NK) G1_DMA(1 - cur, kt + 1);
#pragma unroll
        for (int kk = 0; kk < 2; kk++) {
            int cq = kk * 4 + quad;
            bf16x8 a[4], b[4];
#pragma unroll
            for (int mt = 0; mt < 4; mt++) {
                int m = wm + mt * 16 + l15;
                a[mt] = *(const bf16x8*)&As[cur][m * 64 + ((cq + m) & 7) * 8];
            }
#pragma unroll
            for (int nt = 0; nt < 4; nt++) {
                int n = wn + nt * 16 + l15;
                b[nt] = *(const bf16x8*)&Bs[cur][n * 64 + ((cq + n) & 7) * 8];
            }
#pragma unroll
            for (int mt = 0; mt < 4; mt++)
#pragma unroll
                for (int nt = 0; nt < 4; nt++)
                    acc[mt][nt] = __builtin_amdgcn_mfma_f32_16x16x32_bf16(
                        a[mt], b[nt], acc[mt][nt], 0, 0, 0);
        }
    }

    const float* b1e = b1 + e * FFN + n0;
#pragma unroll
    for (int mt = 0; mt < 4; mt++) {
        int rbase = wm + mt * 16 + quad * 4;
#pragma unroll
        for (int nt = 0; nt < 4; nt++) {
            int coln = wn + nt * 16 + l15;
            float bb = b1e[coln];
#pragma unroll
            for (int r = 0; r < 4; r++) {
                int p = t0 + rbase + r;
                if (p < count)
                    hg[(size_t)(off + p) * FFN + n0 + coln] =
                        f2bf(gelu_exact(acc[mt][nt][r] + bb));
            }
        }
    }
}

// ---- GEMM2: out[tok] += hg_gathered @ W2T  (split-K x2, atomic) ------------
// grid (HID/128, MAX_SLOTS, 2).
__global__ __launch_bounds__(256) void gemm2_kernel(
        const short* __restrict__ hg, const short* __restrict__ W2T,
        const int* __restrict__ offs, const int* __restrict__ cnts,
        const int* __restrict__ tokl,
        const int* __restrict__ slot_e, const int* __restrict__ slot_t0,
        float* __restrict__ out) {
    int s = blockIdx.y;
    int e = slot_e[s];
    if (e < 0) return;
    int t0 = slot_t0[s], count = cnts[e], off = offs[e];
    int ks = blockIdx.z;
    int n0 = blockIdx.x * 128;

    __shared__ short As[2][128 * 64];
    __shared__ short Bs[2][128 * 64];

    int tid = threadIdx.x;
    int w = tid >> 6, l = tid & 63, l15 = l & 15, quad = l >> 4;
    int wm = (w >> 1) * 64, wn = (w & 1) * 64;

    const short* srcA[4];
#pragma unroll
    for (int i = 0; i < 4; i++) {
        int row = w * 32 + i * 8 + (l >> 3);
        int c = ((l & 7) - row) & 7;
        int p = t0 + row;
        int g = off + (p < count ? p : count - 1);
        srcA[i] = hg + (size_t)g * FFN + ks * 1024 + c * 8;
    }
    int sbase = w * 2048 + l * 8;

    const short* Bpan = W2T + (size_t)e * (FFN * HID)
                      + (size_t)(n0 >> 7) * ((FFN >> 6) * 8192)
                      + (size_t)ks * 16 * 8192;

    f32x4 acc[4][4];
#pragma unroll
    for (int i = 0; i < 4; i++)
#pragma unroll
        for (int j = 0; j < 4; j++) acc[i][j] = (f32x4){0.f, 0.f, 0.f, 0.f};

#define G2_DMA(BUF, KT) {                                                    \
    _Pragma("unroll") for (int i = 0; i < 4; i++)                            \
        async_cp16(srcA[i] + (KT) * 64, &As[BUF][sbase + i * 512]);          \
    const short* bp = Bpan + (size_t)(KT) * 8192;                            \
    _Pragma("unroll") for (int i = 0; i < 4; i++)                            \
        async_cp16(bp + sbase + i * 512, &Bs[BUF][sbase + i * 512]); }

    G2_DMA(0, 0);
    const int NK = 16;                   // 1024 / 64
    for (int kt = 0; kt < NK; kt++) {
        __syncthreads();
        int cur = kt & 1;
        if (kt + 1 < NK) G2_DMA(1 - cur, kt + 1);
#pragma unroll
        for (int kk = 0; kk < 2; kk++) {
            int cq = kk * 4 + quad;
            bf16x8 a[4], b[4];
#pragma unroll
            for (int mt = 0; mt < 4; mt++) {
                int m = wm + mt * 16 + l15;
                a[mt] = *(const bf16x8*)&As[cur][m * 64 + ((cq + m) & 7) * 8];
            }
#pragma unroll
            for (int nt = 0; nt < 4; nt++) {
                int n = wn + nt * 16 + l15;
                b[nt] = *(const bf16x8*)&Bs[cur][n * 64 + ((cq + n) & 7) * 8];
            }
#pragma unroll
            for (int mt = 0; mt < 4; mt++)
#pragma unroll
                for (int nt = 0; nt < 4; nt++)
                    acc[mt][nt] = __builtin_amdgcn_mfma_f32_16x16x32_bf16(
                        a[mt], b[nt], acc[mt][nt], 0, 0, 0);
        }
    }

#pragma unroll
    for (int mt = 0; mt < 4; mt++) {
        int rbase = wm + mt * 16 + quad * 4;
#pragma unroll
        for (int nt = 0; nt < 4; nt++) {
            int coln = n0 + wn + nt * 16 + l15;
#pragma unroll
            for (int r = 0; r < 4; r++) {
                int p = t0 + rbase + r;
                if (p < count) {
                    int tok = tokl[off + p];
                    atomicAdd(out + (size_t)tok * HID + coln, acc[mt][nt][r]);
                }
            }
        }
    }
}

extern "C" void kernel_launch(void* const* d_in, const int* in_sizes, int n_in,
                              void* d_out, int out_size, void* d_ws, size_t ws_size,
                              hipStream_t stream) {
    const float* x   = (const float*)d_in[0];
    const int*   idx = (const int*)d_in[1];
    const float* W1  = (const float*)d_in[2];
    const float* b1  = (const float*)d_in[3];
    const float* W2  = (const float*)d_in[4];
    const float* b2  = (const float*)d_in[5];
    float* out = (float*)d_out;

    const size_t META = 32768;
    int*   offs    = (int*)d_ws;
    int*   cnts    = offs + 8;
    int*   tokl    = offs + 16;          // [2048]
    int*   slot_e  = offs + 16 + T_TOK;  // [MAX_SLOTS]
    int*   slot_t0 = slot_e + MAX_SLOTS;
    char*  base    = (char*)d_ws + META;
    short* xb  = (short*)base;                                    // 4 MB
    short* hg  = (short*)(base + (size_t)T_TOK * HID * 2);        // 8 MB
    short* W1T = (short*)(base + (size_t)T_TOK * HID * 2 + (size_t)T_TOK * FFN * 2);
    short* W2T = W1T + (size_t)NEXP * FFN * HID;                  // 32 MB each

    // blocks: [0,1024) W1T | [1024,2048) W2T | [2048,3072) xcvt
    //         [3072,5120) initout | 5120 bucket
    prep_kernel<<<5121, 256, 0, stream>>>(
        x, idx, b2, W1, W2, xb, out, W1T, W2T,
        offs, cnts, tokl, slot_e, slot_t0);

    gemm1_kernel<<<dim3(FFN / 128, MAX_SLOTS), 256, 0, stream>>>(
        xb, W1T, b1, offs, cnts, tokl, slot_e, slot_t0, hg);
    gemm2_kernel<<<dim3(HID / 128, MAX_SLOTS, 2), 256, 0, stream>>>(
        hg, W2T, offs, cnts, tokl, slot_e, slot_t0, out);
}